// Round 6
// baseline (390.107 us; speedup 1.0000x reference)
//
#include <hip/hip_runtime.h>
#include <hip/hip_bf16.h>
#include <cstddef>

#define D 128
#define BN 32  // nodes per bucket

typedef __attribute__((ext_vector_type(8))) short bf16x8;
typedef __attribute__((ext_vector_type(16))) float f32x16;

static __device__ __forceinline__ unsigned short f2bf(float f) {
  return __builtin_bit_cast(unsigned short, __float2bfloat16(f));
}

__global__ void k_zero(int* __restrict__ p, int n) {
  int i = blockIdx.x * blockDim.x + threadIdx.x;
  if (i < n) p[i] = 0;
}

__global__ void k_deg_count(const int* __restrict__ dst, int e, int* __restrict__ cnt) {
  int i = blockIdx.x * blockDim.x + threadIdx.x;
  if (i < e) atomicAdd(&cnt[dst[i]], 1);
}

// dinv = rsqrt(cnt+1) clamped; bucket histogram bcnt[b] = sum cnt over 32 nodes
__global__ __launch_bounds__(256) void k_dinv_bhist(const int* __restrict__ cnt,
                                                    float* __restrict__ dinv,
                                                    int* __restrict__ bcnt,
                                                    int n, int nb) {
  const int i = blockIdx.x * 256 + threadIdx.x;
  int c = 0;
  if (i < n) {
    c = cnt[i];
    dinv[i] = fminf(rsqrtf((float)(c + 1)), 1.0e6f);
  }
  int s = c;
  s += __shfl_down(s, 16, 32);
  s += __shfl_down(s, 8, 32);
  s += __shfl_down(s, 4, 32);
  s += __shfl_down(s, 2, 32);
  s += __shfl_down(s, 1, 32);
  const int b = i >> 5;
  if ((threadIdx.x & 31) == 0 && b < nb) bcnt[b] = s;
}

// single-block exclusive scan of bcnt[0..nb) (nb <= 4096) -> bbase; bcursor = 0
__global__ __launch_bounds__(256) void k_bscan(const int* __restrict__ bcnt,
                                               int* __restrict__ bbase,
                                               int* __restrict__ bcursor, int nb) {
  __shared__ int sdata[256];
  const int tid = threadIdx.x;
  int loc[16];
  int s = 0;
#pragma unroll
  for (int j = 0; j < 16; ++j) {
    const int idx = tid * 16 + j;
    const int c = (idx < nb) ? bcnt[idx] : 0;
    loc[j] = s; s += c;
  }
  sdata[tid] = s;
  __syncthreads();
  for (int off = 1; off < 256; off <<= 1) {
    int t = (tid >= off) ? sdata[tid - off] : 0;
    __syncthreads();
    sdata[tid] += t;
    __syncthreads();
  }
  const int excl = (tid > 0) ? sdata[tid - 1] : 0;
#pragma unroll
  for (int j = 0; j < 16; ++j) {
    const int idx = tid * 16 + j;
    if (idx < nb) { bbase[idx] = excl + loc[j]; bcursor[idx] = 0; }
  }
}

// pairs[bbase[b]+cursor] = src | (dst&31)<<25  (bucket-sequential -> line-dense writes)
__global__ void k_bucket(const int* __restrict__ src, const int* __restrict__ dst,
                         const int* __restrict__ bbase, int* __restrict__ bcursor,
                         unsigned* __restrict__ pairs, int e) {
  int i = blockIdx.x * blockDim.x + threadIdx.x;
  if (i < e) {
    const int d = dst[i];
    const int b = d >> 5;
    const int pos = bbase[b] + atomicAdd(&bcursor[b], 1);
    pairs[pos] = (unsigned)src[i] | ((unsigned)(d & 31) << 25);
  }
}

// g(bf16) = (x @ W^T + b) * dinv[r] via mfma_f32_32x32x16_bf16 (unchanged from R5)
__global__ __launch_bounds__(256) void k_gemm(
    const float* __restrict__ x, const float* __restrict__ W,
    const float* __restrict__ bias, const float* __restrict__ dinv,
    __hip_bfloat16* __restrict__ g, int n) {
  __shared__ unsigned short xs[128 * 128];
  __shared__ unsigned short Ws[128 * 128];
  const int tid = threadIdx.x;
  const int row0 = blockIdx.x * 128;

#pragma unroll
  for (int u = 0; u < 8; ++u) {
    const int f = tid + 256 * u;
    const int row = f >> 4;
    const int c = f & 15;
    const int ch = (c ^ (row & 7)) << 3;
    {
      const float4* p = reinterpret_cast<const float4*>(&W[(size_t)row * D + c * 8]);
      const float4 v0 = p[0], v1 = p[1];
      uint4 pk;
      pk.x = f2bf(v0.x) | ((unsigned)f2bf(v0.y) << 16);
      pk.y = f2bf(v0.z) | ((unsigned)f2bf(v0.w) << 16);
      pk.z = f2bf(v1.x) | ((unsigned)f2bf(v1.y) << 16);
      pk.w = f2bf(v1.z) | ((unsigned)f2bf(v1.w) << 16);
      *reinterpret_cast<uint4*>(&Ws[row * 128 + ch]) = pk;
    }
    {
      float4 v0 = make_float4(0.f, 0.f, 0.f, 0.f), v1 = v0;
      if (row0 + row < n) {
        const float4* p =
            reinterpret_cast<const float4*>(&x[(size_t)(row0 + row) * D + c * 8]);
        v0 = p[0]; v1 = p[1];
      }
      uint4 pk;
      pk.x = f2bf(v0.x) | ((unsigned)f2bf(v0.y) << 16);
      pk.y = f2bf(v0.z) | ((unsigned)f2bf(v0.w) << 16);
      pk.z = f2bf(v1.x) | ((unsigned)f2bf(v1.y) << 16);
      pk.w = f2bf(v1.z) | ((unsigned)f2bf(v1.w) << 16);
      *reinterpret_cast<uint4*>(&xs[row * 128 + ch]) = pk;
    }
  }
  __syncthreads();

  const int lane = tid & 63;
  const int wv = tid >> 6;
  const int wr = (wv >> 1) * 64;
  const int wc = (wv & 1) * 64;
  const int lr = lane & 31;
  const int lk = lane >> 5;

  f32x16 acc[2][2];
#pragma unroll
  for (int m = 0; m < 2; ++m)
#pragma unroll
    for (int j = 0; j < 2; ++j)
#pragma unroll
      for (int q = 0; q < 16; ++q) acc[m][j][q] = 0.f;

#pragma unroll
  for (int ks = 0; ks < 8; ++ks) {
    bf16x8 a[2], b[2];
#pragma unroll
    for (int m = 0; m < 2; ++m) {
      const int r = wr + m * 32 + lr;
      const int ch = ((ks * 2 + lk) ^ (r & 7)) << 3;
      a[m] = *reinterpret_cast<const bf16x8*>(&xs[r * 128 + ch]);
    }
#pragma unroll
    for (int j = 0; j < 2; ++j) {
      const int r = wc + j * 32 + lr;
      const int ch = ((ks * 2 + lk) ^ (r & 7)) << 3;
      b[j] = *reinterpret_cast<const bf16x8*>(&Ws[r * 128 + ch]);
    }
#pragma unroll
    for (int m = 0; m < 2; ++m)
#pragma unroll
      for (int j = 0; j < 2; ++j)
        acc[m][j] = __builtin_amdgcn_mfma_f32_32x32x16_bf16(a[m], b[j], acc[m][j], 0, 0, 0);
  }

#pragma unroll
  for (int m = 0; m < 2; ++m) {
#pragma unroll
    for (int reg = 0; reg < 16; ++reg) {
      const int rloc = (reg & 3) + 8 * (reg >> 2) + 4 * lk;
      const int r = row0 + wr + m * 32 + rloc;
      if (r < n) {
        const float dv = dinv[r];
#pragma unroll
        for (int j = 0; j < 2; ++j) {
          const int col = wc + j * 32 + lr;
          g[(size_t)r * D + col] = __float2bfloat16((acc[m][j][reg] + bias[col]) * dv);
        }
      }
    }
  }
}

// block per bucket: 4 wave-private 32x128 f32 LDS accumulators (64KB, no atomics).
// LDS col layout transposed: x-part at [lane], y-part at [64+lane] -> 2-way (free).
__global__ __launch_bounds__(256) void k_baccum(
    const unsigned* __restrict__ pairs, const int* __restrict__ bbase,
    const int* __restrict__ bcnt, const unsigned* __restrict__ g2,
    const float* __restrict__ dinv, float2* __restrict__ out2, int n) {
  __shared__ float acc[4][BN * 128];
  const int tid = threadIdx.x, w = tid >> 6, lane = tid & 63;
  const int b = blockIdx.x, row0 = b * BN;

  float4* accv = (float4*)acc;
  const float4 z4 = make_float4(0.f, 0.f, 0.f, 0.f);
  for (int i = tid; i < 4 * BN * 32; i += 256) accv[i] = z4;
  __syncthreads();

  const int base = bbase[b];
  const int ecnt = bcnt[b];
  float* __restrict__ my = acc[w];
  const int wbeg = (ecnt * w) >> 2;
  const int wend = (ecnt * (w + 1)) >> 2;
  int k = wbeg;
  for (; k + 8 <= wend; k += 8) {
    unsigned p[8], t[8];
#pragma unroll
    for (int u = 0; u < 8; ++u) p[u] = pairs[base + k + u];
#pragma unroll
    for (int u = 0; u < 8; ++u)
      t[u] = g2[(size_t)(p[u] & 0x1FFFFFFu) * 64 + lane];
#pragma unroll
    for (int u = 0; u < 8; ++u) {
      float* q = &my[(int)(p[u] >> 25) * 128 + lane];
      q[0] += __uint_as_float(t[u] << 16);
      q[64] += __uint_as_float(t[u] & 0xffff0000u);
    }
  }
  for (; k < wend; ++k) {
    const unsigned p = pairs[base + k];
    const unsigned t = g2[(size_t)(p & 0x1FFFFFFu) * 64 + lane];
    float* q = &my[(int)(p >> 25) * 128 + lane];
    q[0] += __uint_as_float(t << 16);
    q[64] += __uint_as_float(t & 0xffff0000u);
  }
  __syncthreads();

  // merge 4 copies + self term, scale by dinv[dst], write out
  for (int idx = tid; idx < BN * 64; idx += 256) {
    const int r = idx >> 6, c2 = idx & 63;
    const int v = row0 + r;
    if (v < n) {
      const int o = r * 128 + c2;
      float sx = acc[0][o] + acc[1][o] + acc[2][o] + acc[3][o];
      float sy = acc[0][o + 64] + acc[1][o + 64] + acc[2][o + 64] + acc[3][o + 64];
      const unsigned t = g2[(size_t)v * 64 + c2];
      sx += __uint_as_float(t << 16);
      sy += __uint_as_float(t & 0xffff0000u);
      const float dv = dinv[v];
      out2[(size_t)v * 64 + c2] = make_float2(sx * dv, sy * dv);
    }
  }
}

extern "C" void kernel_launch(void* const* d_in, const int* in_sizes, int n_in,
                              void* d_out, int out_size, void* d_ws, size_t ws_size,
                              hipStream_t stream) {
  const float* x = (const float*)d_in[0];
  const int* ei = (const int*)d_in[1];
  const float* W = (const float*)d_in[2];
  const float* b = (const float*)d_in[3];
  float* out = (float*)d_out;
  const int n = in_sizes[0] / D;
  const int e = in_sizes[1] / 2;
  const int* src = ei;      // edge_index[0]
  const int* dst = ei + e;  // edge_index[1]
  const int nb = (n + BN - 1) / BN;  // buckets (<=4096 for n<=131072)

  char* ws = (char*)d_ws;
  const size_t nbb = ((size_t)n * 4 + 255) / 256 * 256;
  const size_t kb = ((size_t)nb * 4 + 255) / 256 * 256;
  const size_t eb = ((size_t)e * 4 + 255) / 256 * 256;
  int* cnt = (int*)ws;                       // n ints (in-degree, no self)
  float* dinv = (float*)(ws + nbb);          // n floats
  int* bcnt = (int*)(ws + 2 * nbb);          // nb ints
  int* bbase = (int*)(ws + 2 * nbb + kb);    // nb ints
  int* bcursor = (int*)(ws + 2 * nbb + 2 * kb);  // nb ints
  unsigned* pairs = (unsigned*)(ws + 2 * nbb + 3 * kb);  // e uints
  __hip_bfloat16* g = (__hip_bfloat16*)(ws + 2 * nbb + 3 * kb + eb);  // n*128 bf16

  k_zero<<<(n + 255) / 256, 256, 0, stream>>>(cnt, n);
  k_deg_count<<<(e + 255) / 256, 256, 0, stream>>>(dst, e, cnt);
  k_dinv_bhist<<<(n + 255) / 256, 256, 0, stream>>>(cnt, dinv, bcnt, n, nb);
  k_bscan<<<1, 256, 0, stream>>>(bcnt, bbase, bcursor, nb);
  k_bucket<<<(e + 255) / 256, 256, 0, stream>>>(src, dst, bbase, bcursor, pairs, e);
  k_gemm<<<(n + 127) / 128, 256, 0, stream>>>(x, W, b, dinv, g, n);
  k_baccum<<<nb, 256, 0, stream>>>(pairs, bbase, bcnt, (const unsigned*)g, dinv,
                                   (float2*)out, n);
}

// Round 7
// 227.104 us; speedup vs baseline: 1.7177x; 1.7177x over previous
//
#include <hip/hip_runtime.h>
#include <hip/hip_bf16.h>
#include <cstddef>

#define D 128
#define SHIFT 10          // coarse bucket = 1024 nodes
#define RN (1 << SHIFT)

typedef __attribute__((ext_vector_type(8))) short bf16x8;
typedef __attribute__((ext_vector_type(16))) float f32x16;

static __device__ __forceinline__ unsigned short f2bf(float f) {
  return __builtin_bit_cast(unsigned short, __float2bfloat16(f));
}

__global__ void k_zero(int* __restrict__ p, int n) {
  int i = blockIdx.x * blockDim.x + threadIdx.x;
  if (i < n) p[i] = 0;
}

__global__ void k_deg_count(const int* __restrict__ dst, int e, int* __restrict__ cnt) {
  int i = blockIdx.x * blockDim.x + threadIdx.x;
  if (i < e) atomicAdd(&cnt[dst[i]], 1);
}

// exclusive scan of cnt (1024/block) -> rowptr + block sums; fused dinv
__global__ __launch_bounds__(256) void k_scan1(const int* __restrict__ cnt,
                                               int* __restrict__ rowptr,
                                               int* __restrict__ bsums,
                                               float* __restrict__ dinv, int n) {
  __shared__ int sdata[256];
  const int tid = threadIdx.x;
  const int idx = blockIdx.x * 1024 + tid * 4;
  int v[4], s = 0;
#pragma unroll
  for (int u = 0; u < 4; ++u) {
    int c = 0;
    if (idx + u < n) {
      c = cnt[idx + u];
      dinv[idx + u] = fminf(rsqrtf((float)(c + 1)), 1.0e6f);
    }
    v[u] = s; s += c;
  }
  sdata[tid] = s;
  __syncthreads();
  for (int off = 1; off < 256; off <<= 1) {
    int t = (tid >= off) ? sdata[tid - off] : 0;
    __syncthreads();
    sdata[tid] += t;
    __syncthreads();
  }
  const int excl = (tid > 0) ? sdata[tid - 1] : 0;
#pragma unroll
  for (int u = 0; u < 4; ++u)
    if (idx + u < n) rowptr[idx + u] = excl + v[u];
  if (tid == 255) bsums[blockIdx.x] = sdata[255];
}

__global__ __launch_bounds__(256) void k_scan2(int* __restrict__ bsums, int nb) {
  __shared__ int sdata[256];
  const int tid = threadIdx.x;
  sdata[tid] = (tid < nb) ? bsums[tid] : 0;
  __syncthreads();
  for (int off = 1; off < 256; off <<= 1) {
    int t = (tid >= off) ? sdata[tid - off] : 0;
    __syncthreads();
    sdata[tid] += t;
    __syncthreads();
  }
  const int excl = (tid > 0) ? sdata[tid - 1] : 0;
  if (tid < nb) bsums[tid] = excl;
}

__global__ void k_scan3(int* __restrict__ rowptr, const int* __restrict__ bsums, int n) {
  int i = blockIdx.x * blockDim.x + threadIdx.x;
  if (i < n) rowptr[i] += bsums[i >> 10];
}

__global__ void k_initcur(const int* __restrict__ rowptr, int* __restrict__ gcursor,
                          int nc) {
  int c = blockIdx.x * blockDim.x + threadIdx.x;
  if (c < nc) gcursor[c] = rowptr[c << SHIFT];
}

// block-local counting sort of 4096-edge chunks into 98 coarse buckets.
// One atomicAdd per (block,bucket) claims a contiguous run -> the whole run is
// written by THIS block (one XCD) -> full-line write-back, no cross-XCD frags.
__global__ __launch_bounds__(256) void k_psort(
    const int* __restrict__ src, const int* __restrict__ dst,
    int* __restrict__ gcursor, uint2* __restrict__ pairs, int e, int nc) {
  __shared__ int hist[128];
  __shared__ int gbase[128];
  __shared__ int lcur[128];
  const int tid = threadIdx.x;
  const int base = blockIdx.x * 4096;
  const int m = min(4096, e - base);
  if (tid < nc) hist[tid] = 0;
  __syncthreads();
  int myd[16], mys[16];
#pragma unroll
  for (int j = 0; j < 16; ++j) {
    const int i = tid + j * 256;
    if (i < m) {
      myd[j] = dst[base + i];
      mys[j] = src[base + i];
      atomicAdd(&hist[myd[j] >> SHIFT], 1);
    }
  }
  __syncthreads();
  if (tid < nc) {
    gbase[tid] = atomicAdd(&gcursor[tid], hist[tid]);
    lcur[tid] = 0;
  }
  __syncthreads();
#pragma unroll
  for (int j = 0; j < 16; ++j) {
    const int i = tid + j * 256;
    if (i < m) {
      const int c = myd[j] >> SHIFT;
      const int off = atomicAdd(&lcur[c], 1);
      pairs[gbase[c] + off] = make_uint2((unsigned)mys[j], (unsigned)myd[j]);
    }
  }
}

// one block per coarse bucket: exact per-node scatter via LDS cursors; all
// writes land in this bucket's contiguous srcs region (block-local, L2-dense).
__global__ __launch_bounds__(1024) void k_fine(
    const uint2* __restrict__ pairs, const int* __restrict__ rowptr,
    int* __restrict__ srcs, int n, int e) {
  __shared__ int rowLDS[RN];
  __shared__ int lcur[RN];
  const int c = blockIdx.x;
  const int node0 = c << SHIFT;
  const int nodes = min(RN, n - node0);
  const int tid = threadIdx.x;
  for (int v = tid; v < nodes; v += 1024) {
    rowLDS[v] = rowptr[node0 + v];
    lcur[v] = 0;
  }
  __syncthreads();
  const int beg = rowptr[node0];
  const int end = (node0 + RN < n) ? rowptr[node0 + RN] : e;
  for (int i = beg + tid; i < end; i += 1024) {
    const uint2 p = pairs[i];
    const int lv = (int)p.y - node0;
    const int off = atomicAdd(&lcur[lv], 1);
    srcs[rowLDS[lv] + off] = (int)p.x;
  }
}

// g(bf16) = (x @ W^T + b) * dinv[r] via mfma_f32_32x32x16_bf16 (R5, unchanged)
__global__ __launch_bounds__(256) void k_gemm(
    const float* __restrict__ x, const float* __restrict__ W,
    const float* __restrict__ bias, const float* __restrict__ dinv,
    __hip_bfloat16* __restrict__ g, int n) {
  __shared__ unsigned short xs[128 * 128];
  __shared__ unsigned short Ws[128 * 128];
  const int tid = threadIdx.x;
  const int row0 = blockIdx.x * 128;

#pragma unroll
  for (int u = 0; u < 8; ++u) {
    const int f = tid + 256 * u;
    const int row = f >> 4;
    const int c = f & 15;
    const int ch = (c ^ (row & 7)) << 3;
    {
      const float4* p = reinterpret_cast<const float4*>(&W[(size_t)row * D + c * 8]);
      const float4 v0 = p[0], v1 = p[1];
      uint4 pk;
      pk.x = f2bf(v0.x) | ((unsigned)f2bf(v0.y) << 16);
      pk.y = f2bf(v0.z) | ((unsigned)f2bf(v0.w) << 16);
      pk.z = f2bf(v1.x) | ((unsigned)f2bf(v1.y) << 16);
      pk.w = f2bf(v1.z) | ((unsigned)f2bf(v1.w) << 16);
      *reinterpret_cast<uint4*>(&Ws[row * 128 + ch]) = pk;
    }
    {
      float4 v0 = make_float4(0.f, 0.f, 0.f, 0.f), v1 = v0;
      if (row0 + row < n) {
        const float4* p =
            reinterpret_cast<const float4*>(&x[(size_t)(row0 + row) * D + c * 8]);
        v0 = p[0]; v1 = p[1];
      }
      uint4 pk;
      pk.x = f2bf(v0.x) | ((unsigned)f2bf(v0.y) << 16);
      pk.y = f2bf(v0.z) | ((unsigned)f2bf(v0.w) << 16);
      pk.z = f2bf(v1.x) | ((unsigned)f2bf(v1.y) << 16);
      pk.w = f2bf(v1.z) | ((unsigned)f2bf(v1.w) << 16);
      *reinterpret_cast<uint4*>(&xs[row * 128 + ch]) = pk;
    }
  }
  __syncthreads();

  const int lane = tid & 63;
  const int wv = tid >> 6;
  const int wr = (wv >> 1) * 64;
  const int wc = (wv & 1) * 64;
  const int lr = lane & 31;
  const int lk = lane >> 5;

  f32x16 acc[2][2];
#pragma unroll
  for (int m = 0; m < 2; ++m)
#pragma unroll
    for (int j = 0; j < 2; ++j)
#pragma unroll
      for (int q = 0; q < 16; ++q) acc[m][j][q] = 0.f;

#pragma unroll
  for (int ks = 0; ks < 8; ++ks) {
    bf16x8 a[2], b[2];
#pragma unroll
    for (int m = 0; m < 2; ++m) {
      const int r = wr + m * 32 + lr;
      const int ch = ((ks * 2 + lk) ^ (r & 7)) << 3;
      a[m] = *reinterpret_cast<const bf16x8*>(&xs[r * 128 + ch]);
    }
#pragma unroll
    for (int j = 0; j < 2; ++j) {
      const int r = wc + j * 32 + lr;
      const int ch = ((ks * 2 + lk) ^ (r & 7)) << 3;
      b[j] = *reinterpret_cast<const bf16x8*>(&Ws[r * 128 + ch]);
    }
#pragma unroll
    for (int m = 0; m < 2; ++m)
#pragma unroll
      for (int j = 0; j < 2; ++j)
        acc[m][j] = __builtin_amdgcn_mfma_f32_32x32x16_bf16(a[m], b[j], acc[m][j], 0, 0, 0);
  }

#pragma unroll
  for (int m = 0; m < 2; ++m) {
#pragma unroll
    for (int reg = 0; reg < 16; ++reg) {
      const int rloc = (reg & 3) + 8 * (reg >> 2) + 4 * lk;
      const int r = row0 + wr + m * 32 + rloc;
      if (r < n) {
        const float dv = dinv[r];
#pragma unroll
        for (int j = 0; j < 2; ++j) {
          const int col = wc + j * 32 + lr;
          g[(size_t)r * D + col] = __float2bfloat16((acc[m][j][reg] + bias[col]) * dv);
        }
      }
    }
  }
}

// one wave per node: out[v] = dinv[v]*(g[v] + sum g[s]); bf16 g rows (256B/row)
__global__ __launch_bounds__(256) void k_accum(
    const int* __restrict__ rowptr, const int* __restrict__ cnt,
    const int* __restrict__ srcs, const unsigned int* __restrict__ g2,
    const float* __restrict__ dinv, float* __restrict__ out, int n) {
  const int w = (int)(((size_t)blockIdx.x * 256 + threadIdx.x) >> 6);
  const int lane = threadIdx.x & 63;
  if (w >= n) return;
  const int beg = rowptr[w];
  const int num = cnt[w];
  const unsigned int v = g2[(size_t)w * 64 + lane];  // self-loop term
  float ax = __uint_as_float(v << 16);
  float ay = __uint_as_float(v & 0xffff0000u);
  int k = 0;
  for (; k + 8 <= num; k += 8) {
    unsigned int t[8];
#pragma unroll
    for (int u = 0; u < 8; ++u)
      t[u] = g2[(size_t)srcs[beg + k + u] * 64 + lane];
#pragma unroll
    for (int u = 0; u < 8; ++u) {
      ax += __uint_as_float(t[u] << 16);
      ay += __uint_as_float(t[u] & 0xffff0000u);
    }
  }
  for (; k < num; ++k) {
    const unsigned int t = g2[(size_t)srcs[beg + k] * 64 + lane];
    ax += __uint_as_float(t << 16);
    ay += __uint_as_float(t & 0xffff0000u);
  }
  const float dv = dinv[w];
  ((float2*)out)[(size_t)w * 64 + lane] = make_float2(ax * dv, ay * dv);
}

extern "C" void kernel_launch(void* const* d_in, const int* in_sizes, int n_in,
                              void* d_out, int out_size, void* d_ws, size_t ws_size,
                              hipStream_t stream) {
  const float* x = (const float*)d_in[0];
  const int* ei = (const int*)d_in[1];
  const float* W = (const float*)d_in[2];
  const float* b = (const float*)d_in[3];
  float* out = (float*)d_out;
  const int n = in_sizes[0] / D;
  const int e = in_sizes[1] / 2;
  const int* src = ei;      // edge_index[0]
  const int* dst = ei + e;  // edge_index[1]
  const int nc = (n + RN - 1) >> SHIFT;  // coarse buckets (98 for n=100k)

  char* ws = (char*)d_ws;
  const size_t nbb = ((size_t)n * 4 + 255) / 256 * 256;
  const size_t eb = ((size_t)e * 4 + 255) / 256 * 256;
  int* cnt = (int*)ws;                             // n
  float* dinv = (float*)(ws + nbb);                // n
  int* rowptr = (int*)(ws + 2 * nbb);              // n
  int* bsums = (int*)(ws + 3 * nbb);               // <=512
  int* gcursor = (int*)(ws + 3 * nbb + 2048);      // <=256
  int* srcs = (int*)(ws + 3 * nbb + 4096);         // e
  uint2* pairs = (uint2*)(ws + 3 * nbb + 4096 + eb);       // e uint2
  __hip_bfloat16* g = (__hip_bfloat16*)(ws + 3 * nbb + 4096 + 3 * eb);  // n*128 bf16

  const int nscan = (n + 1023) / 1024;

  k_zero<<<(n + 255) / 256, 256, 0, stream>>>(cnt, n);
  k_deg_count<<<(e + 255) / 256, 256, 0, stream>>>(dst, e, cnt);
  k_scan1<<<nscan, 256, 0, stream>>>(cnt, rowptr, bsums, dinv, n);
  k_scan2<<<1, 256, 0, stream>>>(bsums, nscan);
  k_scan3<<<(n + 255) / 256, 256, 0, stream>>>(rowptr, bsums, n);
  k_initcur<<<1, 256, 0, stream>>>(rowptr, gcursor, nc);
  k_psort<<<(e + 4095) / 4096, 256, 0, stream>>>(src, dst, gcursor, pairs, e, nc);
  k_gemm<<<(n + 127) / 128, 256, 0, stream>>>(x, W, b, dinv, g, n);
  k_fine<<<nc, 1024, 0, stream>>>(pairs, rowptr, srcs, n, e);
  k_accum<<<(n + 3) / 4, 256, 0, stream>>>(rowptr, cnt, srcs, (const unsigned*)g,
                                           dinv, out, n);
}